// Round 5
// baseline (69.299 us; speedup 1.0000x reference)
//
#include <hip/hip_runtime.h>
#include <math.h>

// Problem constants (match reference)
#define PH 7
#define PW 7
#define B_ 4
#define H_ 56
#define W_ 56
#define C_ 256
#define R_ 128

// One workgroup (64 threads = 1 wave) per output bin (r, ph, pw).
// Lane t handles channels [4t, 4t+3] with float4 loads (coalesced: 64*16B = 1KB/inst).
__global__ __launch_bounds__(64) void roi_pool_kernel(
    const float* __restrict__ feat,   // [B,H,W,C]
    const int*   __restrict__ rois,   // [R,5] (b, y1, x1, y2, x2) inclusive
    float*       __restrict__ out)    // [R,PH,PW,C]
{
    const int bin = blockIdx.x;            // r*(PH*PW) + ph*PW + pw
    const int r   = bin / (PH * PW);
    const int pp  = bin - r * (PH * PW);
    const int ph  = pp / PW;
    const int pw  = pp - ph * PW;

    const int b  = rois[r * 5 + 0];
    const int y1 = rois[r * 5 + 1];
    const int x1 = rois[r * 5 + 2];
    const int y2 = rois[r * 5 + 3];
    const int x2 = rois[r * 5 + 4];
    const int rh = y2 - y1 + 1;
    const int rw = x2 - x1 + 1;

    // bin k covers offsets [ceil(k*len/P), ceil((k+1)*len/P) - 1]
    // (partition of [0,len); non-empty whenever len >= P, guaranteed by setup)
    const int hs = y1 + (ph * rh + PH - 1) / PH;
    const int he = y1 + ((ph + 1) * rh + PH - 1) / PH - 1;
    const int ws = x1 + (pw * rw + PW - 1) / PW;
    const int we = x1 + ((pw + 1) * rw + PW - 1) / PW - 1;

    const int c0 = threadIdx.x * 4;
    const float* base = feat + ((size_t)b * H_ * W_) * C_ + c0;

    float4 m = make_float4(-INFINITY, -INFINITY, -INFINITY, -INFINITY);
    for (int y = hs; y <= he; ++y) {
        const float* rowp = base + (size_t)y * W_ * C_;
        for (int x = ws; x <= we; ++x) {
            const float4 v = *reinterpret_cast<const float4*>(rowp + (size_t)x * C_);
            m.x = fmaxf(m.x, v.x);
            m.y = fmaxf(m.y, v.y);
            m.z = fmaxf(m.z, v.z);
            m.w = fmaxf(m.w, v.w);
        }
    }

    // Empty bin (can't happen given setup guarantees, but match reference: -> 0)
    if (hs > he || ws > we) m = make_float4(0.f, 0.f, 0.f, 0.f);

    *reinterpret_cast<float4*>(out + (size_t)bin * C_ + c0) = m;
}

extern "C" void kernel_launch(void* const* d_in, const int* in_sizes, int n_in,
                              void* d_out, int out_size, void* d_ws, size_t ws_size,
                              hipStream_t stream) {
    const float* feat = (const float*)d_in[0];
    const int*   rois = (const int*)d_in[1];
    float*       out  = (float*)d_out;

    const int nbins = R_ * PH * PW;   // 6272 blocks, 1 wave each
    roi_pool_kernel<<<nbins, 64, 0, stream>>>(feat, rois, out);
}

// Round 6
// 67.333 us; speedup vs baseline: 1.0292x; 1.0292x over previous
//
#include <hip/hip_runtime.h>
#include <math.h>

// Problem constants (match reference)
#define PH 7
#define PW 7
#define B_ 4
#define H_ 56
#define W_ 56
#define C_ 256
#define R_ 128

#define BINS_TOTAL (R_ * PH * PW)   // 6272, divisible by 4

// 256 threads = 4 waves per block; each wave owns one output bin.
// Lane t of a wave handles channels [4t,4t+3] via float4 (64*16B = 1KB/inst).
// Pixel loop is flattened and manually 4-deep: 4 independent loads issued
// before any fmax -> memory-level parallelism instead of load->fmax chains.
__global__ __launch_bounds__(256) void roi_pool_kernel(
    const float* __restrict__ feat,   // [B,H,W,C]
    const int*   __restrict__ rois,   // [R,5] (b, y1, x1, y2, x2) inclusive
    float*       __restrict__ out)    // [R,PH,PW,C]
{
    const int wave = threadIdx.x >> 6;
    const int lane = threadIdx.x & 63;
    const int bin  = blockIdx.x * 4 + wave;      // < 6272 always (grid=1568)

    const int r  = bin / (PH * PW);
    const int pp = bin - r * (PH * PW);
    const int ph = pp / PW;
    const int pw = pp - ph * PW;

    const int b  = rois[r * 5 + 0];
    const int y1 = rois[r * 5 + 1];
    const int x1 = rois[r * 5 + 2];
    const int y2 = rois[r * 5 + 3];
    const int x2 = rois[r * 5 + 4];
    const int rh = y2 - y1 + 1;
    const int rw = x2 - x1 + 1;

    // bin k covers offsets [ceil(k*len/P), ceil((k+1)*len/P) - 1] (partition)
    const int hs = y1 + (ph * rh + PH - 1) / PH;
    const int he = y1 + ((ph + 1) * rh + PH - 1) / PH - 1;
    const int ws = x1 + (pw * rw + PW - 1) / PW;
    const int we = x1 + ((pw + 1) * rw + PW - 1) / PW - 1;

    const int nh = he - hs + 1;
    const int nw = we - ws + 1;
    const int total = nh * nw;

    const int c0 = lane * 4;
    const float* base = feat + ((size_t)b * H_ * W_) * C_ + c0;

    // branch-free (y,x) stepper over the bin rectangle
    int y = hs, x = ws;
    #define PIXADDR() (base + ((size_t)y * W_ + x) * C_)
    #define STEP() do { ++x; if (x > we) { x = ws; ++y; } } while (0)

    float4 m = make_float4(-INFINITY, -INFINITY, -INFINITY, -INFINITY);

    int i = 0;
    for (; i + 4 <= total; i += 4) {
        const float* p0 = PIXADDR(); STEP();
        const float* p1 = PIXADDR(); STEP();
        const float* p2 = PIXADDR(); STEP();
        const float* p3 = PIXADDR(); STEP();
        const float4 v0 = *reinterpret_cast<const float4*>(p0);
        const float4 v1 = *reinterpret_cast<const float4*>(p1);
        const float4 v2 = *reinterpret_cast<const float4*>(p2);
        const float4 v3 = *reinterpret_cast<const float4*>(p3);
        m.x = fmaxf(m.x, fmaxf(fmaxf(v0.x, v1.x), fmaxf(v2.x, v3.x)));
        m.y = fmaxf(m.y, fmaxf(fmaxf(v0.y, v1.y), fmaxf(v2.y, v3.y)));
        m.z = fmaxf(m.z, fmaxf(fmaxf(v0.z, v1.z), fmaxf(v2.z, v3.z)));
        m.w = fmaxf(m.w, fmaxf(fmaxf(v0.w, v1.w), fmaxf(v2.w, v3.w)));
    }
    for (; i < total; ++i) {
        const float4 v = *reinterpret_cast<const float4*>(PIXADDR()); STEP();
        m.x = fmaxf(m.x, v.x);
        m.y = fmaxf(m.y, v.y);
        m.z = fmaxf(m.z, v.z);
        m.w = fmaxf(m.w, v.w);
    }

    if (total <= 0) m = make_float4(0.f, 0.f, 0.f, 0.f);  // match reference fixup

    *reinterpret_cast<float4*>(out + (size_t)bin * C_ + c0) = m;
    #undef PIXADDR
    #undef STEP
}

extern "C" void kernel_launch(void* const* d_in, const int* in_sizes, int n_in,
                              void* d_out, int out_size, void* d_ws, size_t ws_size,
                              hipStream_t stream) {
    const float* feat = (const float*)d_in[0];
    const int*   rois = (const int*)d_in[1];
    float*       out  = (float*)d_out;

    roi_pool_kernel<<<BINS_TOTAL / 4, 256, 0, stream>>>(feat, rois, out);
}

// Round 9
// 67.050 us; speedup vs baseline: 1.0335x; 1.0042x over previous
//
#include <hip/hip_runtime.h>
#include <math.h>

// Problem constants (match reference)
#define PH 7
#define PW 7
#define B_ 4
#define H_ 56
#define W_ 56
#define C_ 256
#define R_ 128

#define BINS_TOTAL (R_ * PH * PW)   // 6272, even

// Block: 256 threads = 4 waves = 2 bins x 2 sub-waves.
// The two sub-waves of a bin split its pixel rows (row-interleaved), then
// combine via a 2KB LDS max-reduce. Halves each wave's serialized load
// chain and doubles wave-level parallelism vs 1-wave-per-bin.
// Lane t owns channels [4t,4t+3] (float4: 64*16B = 1KB per load inst).
__global__ __launch_bounds__(256) void roi_pool_kernel(
    const float* __restrict__ feat,   // [B,H,W,C]
    const int*   __restrict__ rois,   // [R,5] (b, y1, x1, y2, x2) inclusive
    float*       __restrict__ out)    // [R,PH,PW,C]
{
    __shared__ float4 red[2][64];

    const int tid      = threadIdx.x;
    const int wave     = tid >> 6;
    const int lane     = tid & 63;
    const int binLocal = wave >> 1;          // 0..1
    const int sub      = wave & 1;           // 0..1 (row parity)
    const int bin      = blockIdx.x * 2 + binLocal;   // < 6272 (grid = 3136)

    const int r  = bin / (PH * PW);
    const int pp = bin - r * (PH * PW);
    const int ph = pp / PW;
    const int pw = pp - ph * PW;

    const int b  = rois[r * 5 + 0];
    const int y1 = rois[r * 5 + 1];
    const int x1 = rois[r * 5 + 2];
    const int y2 = rois[r * 5 + 3];
    const int x2 = rois[r * 5 + 4];
    const int rh = y2 - y1 + 1;
    const int rw = x2 - x1 + 1;

    // bin k covers offsets [ceil(k*len/P), ceil((k+1)*len/P) - 1] (partition)
    const int hs = y1 + (ph * rh + PH - 1) / PH;
    const int he = y1 + ((ph + 1) * rh + PH - 1) / PH - 1;
    const int ws = x1 + (pw * rw + PW - 1) / PW;
    const int we = x1 + ((pw + 1) * rw + PW - 1) / PW - 1;

    const int c0 = lane * 4;
    const float* base = feat + ((size_t)b * H_ * W_) * C_ + c0;

    float4 m = make_float4(-INFINITY, -INFINITY, -INFINITY, -INFINITY);

    // This sub-wave takes rows hs+sub, hs+sub+2, ... (wave-uniform control flow)
    for (int y = hs + sub; y <= he; y += 2) {
        const float* rowp = base + (size_t)y * W_ * C_;
        int x = ws;
        for (; x + 1 <= we; x += 2) {        // 2-deep: issue both loads, then fmax
            const float4 v0 = *reinterpret_cast<const float4*>(rowp + (size_t)x * C_);
            const float4 v1 = *reinterpret_cast<const float4*>(rowp + (size_t)(x + 1) * C_);
            m.x = fmaxf(m.x, fmaxf(v0.x, v1.x));
            m.y = fmaxf(m.y, fmaxf(v0.y, v1.y));
            m.z = fmaxf(m.z, fmaxf(v0.z, v1.z));
            m.w = fmaxf(m.w, fmaxf(v0.w, v1.w));
        }
        if (x <= we) {
            const float4 v = *reinterpret_cast<const float4*>(rowp + (size_t)x * C_);
            m.x = fmaxf(m.x, v.x);
            m.y = fmaxf(m.y, v.y);
            m.z = fmaxf(m.z, v.z);
            m.w = fmaxf(m.w, v.w);
        }
    }

    // Cross-wave max: sub-wave 1 publishes partials, sub-wave 0 combines+stores.
    if (sub) red[binLocal][lane] = m;
    __syncthreads();
    if (!sub) {
        const float4 o = red[binLocal][lane];
        m.x = fmaxf(m.x, o.x);
        m.y = fmaxf(m.y, o.y);
        m.z = fmaxf(m.z, o.z);
        m.w = fmaxf(m.w, o.w);
        // Reference maps non-finite (empty-bin -inf) to 0; bins are never empty
        // given setup guarantees, but keep exact parity.
        m.x = isfinite(m.x) ? m.x : 0.f;
        m.y = isfinite(m.y) ? m.y : 0.f;
        m.z = isfinite(m.z) ? m.z : 0.f;
        m.w = isfinite(m.w) ? m.w : 0.f;
        *reinterpret_cast<float4*>(out + (size_t)bin * C_ + c0) = m;
    }
}

extern "C" void kernel_launch(void* const* d_in, const int* in_sizes, int n_in,
                              void* d_out, int out_size, void* d_ws, size_t ws_size,
                              hipStream_t stream) {
    const float* feat = (const float*)d_in[0];
    const int*   rois = (const int*)d_in[1];
    float*       out  = (float*)d_out;

    roi_pool_kernel<<<BINS_TOTAL / 2, 256, 0, stream>>>(feat, rois, out);
}